// Round 15
// baseline (365.125 us; speedup 1.0000x reference)
//
#include <hip/hip_runtime.h>
#include <math.h>

#define N_NODES 50000
#define IN_DIM 256
#define HEADS 4
#define CDIM 64
#define HC 256        // HEADS*CDIM
#define HOPS 3
#define EDGES 400000
#define NEG_SLOPE 0.2f
#define SEG (EDGES + N_NODES)            // hop0 flat range incl self-loops
#define TOT_E (3 * EDGES + N_NODES)      // flat edge count across hops
#define CAP 32                           // ushort bucket: 64B; P(Poisson(8)+1>32) ~1e-11/node (r6/r7 passed)
#define LOG2E 1.44269504f
#define NRANGE 8                         // dst ranges (one per XCD under round-robin)
#define RANGE_W (N_NODES / NRANGE)       // 6250

// prep_a kernel block ranges (gate+packx | packw | zero-cnt)
#define NB_GATE  ((N_NODES + 3) / 4)             // 12500
#define NB_PACKW ((IN_DIM * 2 * HC) / 256)       // 512
#define NB_ZERO  ((HOPS * N_NODES + 255) / 256)  // 587
#define NB_SCAT  ((TOT_E + 255) / 256)           // 4883
// gemm v4: 64 rows x full 512 cols per block; A LDS once (full K), B direct
// from L2 (WT = 256 KB, L2-resident); NO barriers in the K-loop.
#define GB 64
#define AP 264                                   // A row pad: 132-dw stride -> 2-way free
#define GEMM_BLKS  ((N_NODES + GB - 1) / GB)     // 782
#define FUSED_BLKS (GEMM_BLKS + NRANGE * NB_SCAT) // 782 + 39064 = 39846

typedef unsigned short ushort;
using short8  = __attribute__((ext_vector_type(8))) short;
using floatx4 = __attribute__((ext_vector_type(4))) float;
using f32x2   = __attribute__((ext_vector_type(2))) float;

// flat layout: hop0 [0, E+N) incl self-loops ; hop1 [SEG, SEG+E) ; hop2 [...]
__device__ __forceinline__ void decode_flat(int f, int& k, int& e)
{
    if (f < SEG)              { k = 0; e = f; }
    else if (f < SEG + EDGES) { k = 1; e = f - SEG; }
    else                      { k = 2; e = f - SEG - EDGES; }
}

__device__ __forceinline__ ushort f2bf(float f)
{
    unsigned u = __float_as_uint(f);
    unsigned r = u + 0x7fffu + ((u >> 16) & 1u);   // RNE
    return (ushort)(r >> 16);
}

// raw v_exp_f32: D = 2^S0 (no libm fixup; matches __expf's internal use)
__device__ __forceinline__ float exp2_raw(float x)
{
    float r;
    asm volatile("v_exp_f32 %0, %1" : "=v"(r) : "v"(x));
    return r;
}

// DPP-based xor-add within groups of 8 lanes (3 VALU adds on the critical
// chain; replaces 3 ds_swizzle). CTRL must be a literal -> template param.
template <int CTRL>
__device__ __forceinline__ float dpp_xadd(float x)
{
    int y = __builtin_amdgcn_update_dpp(
        0, __float_as_int(x), CTRL, 0xF, 0xF, true);
    return x + __int_as_float(y);
}
#define DPP_XOR1 0xB1    // quad_perm [1,0,3,2]
#define DPP_XOR2 0x4E    // quad_perm [2,3,0,1]
#define DPP_HMIR 0x141   // row_half_mirror: partner in the other quad of 8

// unpack 2 bf16 (packed in a uint) -> f32x2 {lo, hi}
__device__ __forceinline__ f32x2 bf2x(unsigned u)
{
    f32x2 r;
    r.x = __uint_as_float(u << 16);
    r.y = __uint_as_float(u & 0xffff0000u);
    return r;
}

// leaky-relu slope 0.2: max(v, 0.2v)  -> v_pk_mul_f32 + v_pk_max_f32
__device__ __forceinline__ f32x2 lrelu2(f32x2 v)
{
    return __builtin_elementwise_max(v, 0.2f * v);
}

// ---------------------------------------------------------------------------
// prep_a: [gate+pack_x | pack_w | zero-cnt] (unchanged).
// ---------------------------------------------------------------------------
__global__ __launch_bounds__(256) void prep_a(
    const float* __restrict__ X, const float* __restrict__ Wg,
    const float* __restrict__ bg, float* __restrict__ gw,
    ushort* __restrict__ Xb,
    const float* __restrict__ Wl, const float* __restrict__ Wr,
    ushort* __restrict__ WT, int* __restrict__ cnt)
{
    const int blk = blockIdx.x;
    const int tid = threadIdx.x;

    if (blk < NB_GATE) {
        // ---- gate + bf16 pack of x: one wave per node ----
        const int node = (blk * 256 + tid) >> 6;
        const int lane = tid & 63;
        if (node >= N_NODES) return;

        float4 xv = ((const float4*)(X + (size_t)node * IN_DIM))[lane];

        union { ushort s[4]; uint2 u; } o;
        o.s[0] = f2bf(xv.x); o.s[1] = f2bf(xv.y);
        o.s[2] = f2bf(xv.z); o.s[3] = f2bf(xv.w);
        ((uint2*)(Xb + (size_t)node * IN_DIM))[lane] = o.u;

        float a0 = 0.f, a1 = 0.f, a2 = 0.f;
        const int i0 = lane * 4;
        a0 += xv.x * Wg[(i0 + 0) * HOPS + 0]; a1 += xv.x * Wg[(i0 + 0) * HOPS + 1]; a2 += xv.x * Wg[(i0 + 0) * HOPS + 2];
        a0 += xv.y * Wg[(i0 + 1) * HOPS + 0]; a1 += xv.y * Wg[(i0 + 1) * HOPS + 1]; a2 += xv.y * Wg[(i0 + 1) * HOPS + 2];
        a0 += xv.z * Wg[(i0 + 2) * HOPS + 0]; a1 += xv.z * Wg[(i0 + 2) * HOPS + 1]; a2 += xv.z * Wg[(i0 + 2) * HOPS + 2];
        a0 += xv.w * Wg[(i0 + 3) * HOPS + 0]; a1 += xv.w * Wg[(i0 + 3) * HOPS + 1]; a2 += xv.w * Wg[(i0 + 3) * HOPS + 2];

        #pragma unroll
        for (int off = 32; off >= 1; off >>= 1) {
            a0 += __shfl_xor(a0, off);
            a1 += __shfl_xor(a1, off);
            a2 += __shfl_xor(a2, off);
        }
        if (lane == 0) {
            float l0 = a0 + bg[0], l1 = a1 + bg[1], l2 = a2 + bg[2];
            float m = fmaxf(l0, fmaxf(l1, l2));
            float e0 = expf(l0 - m), e1 = expf(l1 - m), e2 = expf(l2 - m);
            float inv = 1.f / (e0 + e1 + e2);
            gw[node * HOPS + 0] = e0 * inv;
            gw[node * HOPS + 1] = e1 * inv;
            gw[node * HOPS + 2] = e2 * inv;
        }
    } else if (blk < NB_GATE + NB_PACKW) {
        // ---- pack W: WT[n][k]; coalesced writes, gather reads (W L2-resident)
        int id = (blk - NB_GATE) * 256 + tid;
        int n = id >> 8;            // 0..511
        int k = id & 255;           // 0..255
        float v = (n < HC) ? Wl[k * HC + n] : Wr[k * HC + (n - HC)];
        WT[(size_t)n * IN_DIM + k] = f2bf(v);
    } else {
        // ---- zero cnt (folded memset; completes before gemm_scatter's atomics)
        int id = (blk - NB_GATE - NB_PACKW) * 256 + tid;
        if (id < HOPS * N_NODES) cnt[id] = 0;
    }
}

// ---------------------------------------------------------------------------
// gemm_scatter v5: blocks [0,782) = gemm v4 (unchanged). Blocks [782, 39846)
// = dst-range-partitioned scatter: sblk = blk-782; range = sblk&7 (== XCD id
// under round-robin dispatch); chunk = sblk>>3. Each block reads its 256
// edges but commits only those with dst/6250 == range -> each XCD's L2 holds
// only its 1.2 MB bucket slice; lines accumulate all writes before ONE
// writeback (was: 1.25M sector-granular random HBM writes ~ 70 MB at <1 TB/s
// = the old kernel's 110 µs drain). ei re-reads x8 are L3-resident.
// ---------------------------------------------------------------------------
__global__ __launch_bounds__(256, 2) void gemm_scatter(
    const ushort* __restrict__ Xb, const ushort* __restrict__ WT,
    const float* __restrict__ b_l, const float* __restrict__ b_r,
    ushort* __restrict__ xlb, ushort* __restrict__ xrb, int M,
    const int* __restrict__ ei0, const int* __restrict__ ei1,
    const int* __restrict__ ei2, int* __restrict__ cnt,
    ushort* __restrict__ bucket)
{
    __shared__ ushort As[GB][AP];        // 64 x 264 x 2B = 33,792 B
    const int blk = blockIdx.x;
    const int tid = threadIdx.x;

    if (blk >= GEMM_BLKS) {
        // ---- dst-range-partitioned bucket scatter ----
        const int sblk  = blk - GEMM_BLKS;
        const int range = sblk & (NRANGE - 1);   // XCD-affine (perf-only assumption)
        const int chunk = sblk >> 3;
        int f = chunk * 256 + tid;
        if (f >= TOT_E) return;
        int k, e; decode_flat(f, k, e);
        int s, d;
        if (k == 0 && e >= EDGES) { s = d = e - EDGES; }
        else {
            const int* ei = (k == 0) ? ei0 : (k == 1) ? ei1 : ei2;
            s = ei[e]; d = ei[EDGES + e];
        }
        if (d / RANGE_W != range) return;        // not this block's dst slice
        int pos = atomicAdd(&cnt[k * N_NODES + d], 1);
        if (pos < CAP)
            bucket[((size_t)k * N_NODES + d) * CAP + pos] = (ushort)s;
        return;
    }

    const int wave = tid >> 6, lane = tid & 63;
    const int row0 = blk * GB;
    const int wx   = wave * 128;         // this wave's output-col base
    const int lrow = lane & 15, lk = (lane >> 4) * 8;

    // ---- stage full-K A tile once: 64 rows x 256 cols bf16 ----
    #pragma unroll
    for (int j = 0; j < 8; j++) {
        int id = tid + 256 * j;          // 0..2047
        int r  = id >> 5;                // 32 uint4-slots per 512B row
        int c  = (id & 31) * 8;
        int gr = row0 + r;
        uint4 v = make_uint4(0u, 0u, 0u, 0u);
        if (gr < M)
            v = *(const uint4*)(Xb + (size_t)gr * IN_DIM + c);
        *(uint4*)&As[r][c] = v;
    }
    __syncthreads();                     // the ONLY barrier

    floatx4 acc[4][8];
    #pragma unroll
    for (int i = 0; i < 4; i++)
        #pragma unroll
        for (int j = 0; j < 8; j++)
            acc[i][j] = (floatx4){0.f, 0.f, 0.f, 0.f};

    #pragma unroll 2
    for (int k0 = 0; k0 < IN_DIM; k0 += 32) {
        short8 af[4], bf[8];
        #pragma unroll
        for (int ni = 0; ni < 8; ni++)
            bf[ni] = *(const short8*)(WT +
                (size_t)(wx + ni * 16 + lrow) * IN_DIM + k0 + lk);
        #pragma unroll
        for (int mi = 0; mi < 4; mi++)
            af[mi] = *(const short8*)&As[mi * 16 + lrow][k0 + lk];

        #pragma unroll
        for (int mi = 0; mi < 4; mi++)
            #pragma unroll
            for (int ni = 0; ni < 8; ni++)
                acc[mi][ni] = __builtin_amdgcn_mfma_f32_16x16x32_bf16(
                    bf[ni], af[mi], acc[mi][ni], 0, 0, 0);
    }

    const int csub = (lane >> 4) * 4;
    const bool left = (wx < HC);         // wave-uniform: waves 0,1 -> xlb; 2,3 -> xrb
    const float*  bvec = left ? b_l : b_r;
    ushort*       obuf = left ? xlb : xrb;
    const int     cbase = left ? wx : wx - HC;
    #pragma unroll
    for (int mi = 0; mi < 4; mi++) {
        int grow = row0 + mi * 16 + lrow;
        if (grow < M) {
            #pragma unroll
            for (int ni = 0; ni < 8; ni++) {
                int lc = cbase + ni * 16 + csub;
                floatx4 v = acc[mi][ni];
                const float4 b = *(const float4*)(bvec + lc);
                union { ushort s[4]; uint2 u; } o;
                o.s[0] = f2bf(v[0] + b.x);
                o.s[1] = f2bf(v[1] + b.y);
                o.s[2] = f2bf(v[2] + b.z);
                o.s[3] = f2bf(v[3] + b.w);
                *(uint2*)(obuf + (size_t)grow * HC + lc) = o.u;
            }
        }
    }
}

// ---------------------------------------------------------------------------
// node_all v10 (DPP head-reduce; bucket now ushort): measured 125.6-126.5 µs.
// ---------------------------------------------------------------------------
__global__ __launch_bounds__(192) void node_all(
    const ushort* __restrict__ xlb, const ushort* __restrict__ xrb,
    const int* __restrict__ cnt, const ushort* __restrict__ bucket,
    const float* __restrict__ att, const float* __restrict__ gw,
    const float* __restrict__ bias, float* __restrict__ out)
{
    __shared__ float lds[HOPS][CDIM];
    const int n    = blockIdx.x;
    const int k    = threadIdx.x >> 6;   // hop
    const int lane = threadIdx.x & 63;
    const int half = lane >> 5;          // which edge of the pair
    const int sub  = lane & 31;          // channel group: ch = sub*8 .. sub*8+7
    const unsigned laneoff = (unsigned)sub * 8;

    const int deg = min(cnt[k * N_NODES + n], CAP);
    const ushort* bk = bucket + ((size_t)k * N_NODES + n) * CAP;

    // xr channels for this lane (bf16 -> f32x2 pairs)
    uint4 rq = *(const uint4*)(xrb + (size_t)n * HC + laneoff);
    f32x2 rr[4] = { bf2x(rq.x), bf2x(rq.y), bf2x(rq.z), bf2x(rq.w) };

    // att pre-scaled by LOG2E: p is a log2-domain logit -> raw v_exp_f32
    const float4 a0 = ((const float4*)(att + (size_t)k * HC))[sub * 2 + 0];
    const float4 a1 = ((const float4*)(att + (size_t)k * HC))[sub * 2 + 1];
    f32x2 w2[4] = { {a0.x * LOG2E, a0.y * LOG2E}, {a0.z * LOG2E, a0.w * LOG2E},
                    {a1.x * LOG2E, a1.y * LOG2E}, {a1.z * LOG2E, a1.w * LOG2E} };

    float denom = 0.f;
    f32x2 acc2[4] = { {0.f,0.f}, {0.f,0.f}, {0.f,0.f}, {0.f,0.f} };

    if (deg > 0) {
        const int degm1 = deg - 1;
        int myS = (lane < deg) ? (int)bk[lane] : 0;
        const int npair = (deg + 1) >> 1;

        int s0 = __shfl(myS, min(half, degm1));
        uint4 q = *(const uint4*)(xlb + (unsigned)s0 * HC + laneoff);

        for (int j = 0; j < npair; j++) {
            int sn = __shfl(myS, min(2 * (j + 1) + half, degm1));
            uint4 qn = *(const uint4*)(xlb + (unsigned)sn * HC + laneoff);

            f32x2 f0 = bf2x(q.x), f1 = bf2x(q.y);
            f32x2 f2 = bf2x(q.z), f3 = bf2x(q.w);

            f32x2 pp = w2[0] * lrelu2(f0 + rr[0]);
            pp = __builtin_elementwise_fma(w2[1], lrelu2(f1 + rr[1]), pp);
            pp = __builtin_elementwise_fma(w2[2], lrelu2(f2 + rr[2]), pp);
            pp = __builtin_elementwise_fma(w2[3], lrelu2(f3 + rr[3]), pp);
            float p = pp.x + pp.y;

            // per-head reduce over 8 lanes: 3 DPP VALU adds
            p = dpp_xadd<DPP_XOR1>(p);
            p = dpp_xadd<DPP_XOR2>(p);
            p = dpp_xadd<DPP_HMIR>(p);

            bool valid = (2 * j + half) < deg;
            float ex = valid ? exp2_raw(p) : 0.f;
            denom += ex;
            f32x2 ex2 = { ex, ex };
            acc2[0] = __builtin_elementwise_fma(ex2, f0, acc2[0]);
            acc2[1] = __builtin_elementwise_fma(ex2, f1, acc2[1]);
            acc2[2] = __builtin_elementwise_fma(ex2, f2, acc2[2]);
            acc2[3] = __builtin_elementwise_fma(ex2, f3, acc2[3]);
            q = qn;
        }
    }

    // merge halves (xor-32): denom & acc are per-head after this.
    denom += __shfl_xor(denom, 32);
    const float inv = (denom > 0.f) ? 1.f / denom : 0.f;
    const float g   = gw[n * HOPS + k];
    const float* bb = bias + (size_t)k * CDIM + (size_t)(sub & 7) * 8;

    // per-head normalize FIRST, THEN head mean (xor-8, xor-16).
    #pragma unroll
    for (int i = 0; i < 4; i++) {
        acc2[i].x += __shfl_xor(acc2[i].x, 32);
        acc2[i].y += __shfl_xor(acc2[i].y, 32);
        acc2[i].x *= inv;
        acc2[i].y *= inv;
        acc2[i].x += __shfl_xor(acc2[i].x, 8);
        acc2[i].y += __shfl_xor(acc2[i].y, 8);
        acc2[i].x += __shfl_xor(acc2[i].x, 16);
        acc2[i].y += __shfl_xor(acc2[i].y, 16);
        if (lane < 8) {
            lds[k][lane * 8 + 2 * i]     = g * (acc2[i].x * 0.25f + bb[2 * i]);
            lds[k][lane * 8 + 2 * i + 1] = g * (acc2[i].y * 0.25f + bb[2 * i + 1]);
        }
    }
    __syncthreads();

    if (threadIdx.x < CDIM)
        out[(size_t)n * CDIM + threadIdx.x] =
            lds[0][threadIdx.x] + lds[1][threadIdx.x] + lds[2][threadIdx.x];
}

// ---------------------------------------------------------------------------
extern "C" void kernel_launch(void* const* d_in, const int* in_sizes, int n_in,
                              void* d_out, int out_size, void* d_ws, size_t ws_size,
                              hipStream_t stream)
{
    const float* x      = (const float*)d_in[0];
    const int*   ei0    = (const int*)d_in[1];
    const int*   ei1    = (const int*)d_in[2];
    const int*   ei2    = (const int*)d_in[3];
    const float* W_l    = (const float*)d_in[4];
    const float* b_l    = (const float*)d_in[5];
    const float* W_r    = (const float*)d_in[6];
    const float* b_r    = (const float*)d_in[7];
    const float* att    = (const float*)d_in[8];   // [3,4,64]
    const float* bias   = (const float*)d_in[9];   // [3,64]
    const float* W_gate = (const float*)d_in[10];  // [256,3]
    const float* b_gate = (const float*)d_in[11];  // [3]

    const size_t NHC = (size_t)N_NODES * HC;       // 12,800,000
    float* ws      = (float*)d_ws;
    float* gwbuf   = ws;                           // 150,000 floats
    int*   cnt     = (int*)(gwbuf + HOPS * N_NODES);         // 150,000 ints
    ushort* bucket = (ushort*)(cnt + HOPS * N_NODES);        // 3*N*CAP ushorts = 9.6 MB
    ushort* xlb    = bucket + (size_t)HOPS * N_NODES * CAP;  // NHC bf16
    ushort* xrb    = xlb + NHC;                    // NHC bf16
    ushort* Xb     = xrb + NHC;                    // NHC bf16
    ushort* WT     = Xb + NHC;                     // 131,072 bf16

    // gate + pack_x | pack_w | zero-cnt (memset folded in; no extra launch)
    prep_a<<<NB_GATE + NB_PACKW + NB_ZERO, 256, 0, stream>>>(
        x, W_gate, b_gate, gwbuf, Xb, W_l, W_r, WT, cnt);

    // gemm v4 + dst-range-partitioned scatter (XCD-local bucket writes)
    gemm_scatter<<<FUSED_BLKS, 256, 0, stream>>>(
        Xb, WT, b_l, b_r, xlb, xrb, N_NODES,
        ei0, ei1, ei2, cnt, bucket);

    // fused logits + softmax + aggregate + head-mean + gate combine
    node_all<<<N_NODES, 192, 0, stream>>>(
        xlb, xrb, cnt, bucket, att, gwbuf, bias, (float*)d_out);
}

// Round 16
// 327.823 us; speedup vs baseline: 1.1138x; 1.1138x over previous
//
#include <hip/hip_runtime.h>
#include <math.h>

#define N_NODES 50000
#define IN_DIM 256
#define HEADS 4
#define CDIM 64
#define HC 256        // HEADS*CDIM
#define HOPS 3
#define EDGES 400000
#define NEG_SLOPE 0.2f
#define SEG (EDGES + N_NODES)            // hop0 flat range incl self-loops
#define TOT_E (3 * EDGES + N_NODES)      // flat edge count across hops
#define CAP 32                           // ushort bucket row = 64B = one line; P(deg>32) ~1e-11 (r6/r7/r15 passed)
#define LOG2E 1.44269504f

// prep_a kernel block ranges (gate+packx | packw | zero-cnt)
#define NB_GATE  ((N_NODES + 3) / 4)             // 12500
#define NB_PACKW ((IN_DIM * 2 * HC) / 256)       // 512
#define NB_ZERO  ((HOPS * N_NODES + 255) / 256)  // 587
#define NB_SCAT  ((TOT_E + 255) / 256)           // 4883
// gemm v4: 64 rows x full 512 cols per block; A LDS once (full K), B direct
// from L2 (WT = 256 KB, L2-resident); NO barriers in the K-loop.
#define GB 64
#define AP 264                                   // A row pad: 132-dw stride -> 2-way free
#define GEMM_BLKS  ((N_NODES + GB - 1) / GB)     // 782
#define FUSED_BLKS (GEMM_BLKS + NB_SCAT)         // 5665

typedef unsigned short ushort;
using short8  = __attribute__((ext_vector_type(8))) short;
using floatx4 = __attribute__((ext_vector_type(4))) float;
using f32x2   = __attribute__((ext_vector_type(2))) float;

// flat layout: hop0 [0, E+N) incl self-loops ; hop1 [SEG, SEG+E) ; hop2 [...]
__device__ __forceinline__ void decode_flat(int f, int& k, int& e)
{
    if (f < SEG)              { k = 0; e = f; }
    else if (f < SEG + EDGES) { k = 1; e = f - SEG; }
    else                      { k = 2; e = f - SEG - EDGES; }
}

__device__ __forceinline__ ushort f2bf(float f)
{
    unsigned u = __float_as_uint(f);
    unsigned r = u + 0x7fffu + ((u >> 16) & 1u);   // RNE
    return (ushort)(r >> 16);
}

// raw v_exp_f32: D = 2^S0 (no libm fixup; matches __expf's internal use)
__device__ __forceinline__ float exp2_raw(float x)
{
    float r;
    asm volatile("v_exp_f32 %0, %1" : "=v"(r) : "v"(x));
    return r;
}

// DPP-based xor-add within groups of 8 lanes (3 VALU adds on the critical
// chain; replaces 3 ds_swizzle). CTRL must be a literal -> template param.
template <int CTRL>
__device__ __forceinline__ float dpp_xadd(float x)
{
    int y = __builtin_amdgcn_update_dpp(
        0, __float_as_int(x), CTRL, 0xF, 0xF, true);
    return x + __int_as_float(y);
}
#define DPP_XOR1 0xB1    // quad_perm [1,0,3,2]
#define DPP_XOR2 0x4E    // quad_perm [2,3,0,1]
#define DPP_HMIR 0x141   // row_half_mirror: partner in the other quad of 8

// unpack 2 bf16 (packed in a uint) -> f32x2 {lo, hi}
__device__ __forceinline__ f32x2 bf2x(unsigned u)
{
    f32x2 r;
    r.x = __uint_as_float(u << 16);
    r.y = __uint_as_float(u & 0xffff0000u);
    return r;
}

// leaky-relu slope 0.2: max(v, 0.2v)  -> v_pk_mul_f32 + v_pk_max_f32
__device__ __forceinline__ f32x2 lrelu2(f32x2 v)
{
    return __builtin_elementwise_max(v, 0.2f * v);
}

// ---------------------------------------------------------------------------
// prep_a: [gate+pack_x | pack_w | zero-cnt] (unchanged).
// ---------------------------------------------------------------------------
__global__ __launch_bounds__(256) void prep_a(
    const float* __restrict__ X, const float* __restrict__ Wg,
    const float* __restrict__ bg, float* __restrict__ gw,
    ushort* __restrict__ Xb,
    const float* __restrict__ Wl, const float* __restrict__ Wr,
    ushort* __restrict__ WT, int* __restrict__ cnt)
{
    const int blk = blockIdx.x;
    const int tid = threadIdx.x;

    if (blk < NB_GATE) {
        // ---- gate + bf16 pack of x: one wave per node ----
        const int node = (blk * 256 + tid) >> 6;
        const int lane = tid & 63;
        if (node >= N_NODES) return;

        float4 xv = ((const float4*)(X + (size_t)node * IN_DIM))[lane];

        union { ushort s[4]; uint2 u; } o;
        o.s[0] = f2bf(xv.x); o.s[1] = f2bf(xv.y);
        o.s[2] = f2bf(xv.z); o.s[3] = f2bf(xv.w);
        ((uint2*)(Xb + (size_t)node * IN_DIM))[lane] = o.u;

        float a0 = 0.f, a1 = 0.f, a2 = 0.f;
        const int i0 = lane * 4;
        a0 += xv.x * Wg[(i0 + 0) * HOPS + 0]; a1 += xv.x * Wg[(i0 + 0) * HOPS + 1]; a2 += xv.x * Wg[(i0 + 0) * HOPS + 2];
        a0 += xv.y * Wg[(i0 + 1) * HOPS + 0]; a1 += xv.y * Wg[(i0 + 1) * HOPS + 1]; a2 += xv.y * Wg[(i0 + 1) * HOPS + 2];
        a0 += xv.z * Wg[(i0 + 2) * HOPS + 0]; a1 += xv.z * Wg[(i0 + 2) * HOPS + 1]; a2 += xv.z * Wg[(i0 + 2) * HOPS + 2];
        a0 += xv.w * Wg[(i0 + 3) * HOPS + 0]; a1 += xv.w * Wg[(i0 + 3) * HOPS + 1]; a2 += xv.w * Wg[(i0 + 3) * HOPS + 2];

        #pragma unroll
        for (int off = 32; off >= 1; off >>= 1) {
            a0 += __shfl_xor(a0, off);
            a1 += __shfl_xor(a1, off);
            a2 += __shfl_xor(a2, off);
        }
        if (lane == 0) {
            float l0 = a0 + bg[0], l1 = a1 + bg[1], l2 = a2 + bg[2];
            float m = fmaxf(l0, fmaxf(l1, l2));
            float e0 = expf(l0 - m), e1 = expf(l1 - m), e2 = expf(l2 - m);
            float inv = 1.f / (e0 + e1 + e2);
            gw[node * HOPS + 0] = e0 * inv;
            gw[node * HOPS + 1] = e1 * inv;
            gw[node * HOPS + 2] = e2 * inv;
        }
    } else if (blk < NB_GATE + NB_PACKW) {
        // ---- pack W: WT[n][k]; coalesced writes, gather reads (W L2-resident)
        int id = (blk - NB_GATE) * 256 + tid;
        int n = id >> 8;            // 0..511
        int k = id & 255;           // 0..255
        float v = (n < HC) ? Wl[k * HC + n] : Wr[k * HC + (n - HC)];
        WT[(size_t)n * IN_DIM + k] = f2bf(v);
    } else {
        // ---- zero cnt (folded memset; completes before gemm_scatter's atomics)
        int id = (blk - NB_GATE - NB_PACKW) * 256 + tid;
        if (id < HOPS * N_NODES) cnt[id] = 0;
    }
}

// ---------------------------------------------------------------------------
// gemm_scatter v6: blocks [0,782) = gemm v4 (unchanged). Blocks [782, 5665)
// = SINGLE-PASS scatter with ushort bucket (CAP=32): bucket array 24->9.6 MB,
// so the L2-ping-pong write amplification (~2.9x array footprint; r14/r15
// counters) drops ~70 -> ~28 MB with NO extra reads and NO extra blocks
// (r15's 8-range partition saved writes but its 8x ei re-reads cost more).
// ---------------------------------------------------------------------------
__global__ __launch_bounds__(256, 2) void gemm_scatter(
    const ushort* __restrict__ Xb, const ushort* __restrict__ WT,
    const float* __restrict__ b_l, const float* __restrict__ b_r,
    ushort* __restrict__ xlb, ushort* __restrict__ xrb, int M,
    const int* __restrict__ ei0, const int* __restrict__ ei1,
    const int* __restrict__ ei2, int* __restrict__ cnt,
    ushort* __restrict__ bucket)
{
    __shared__ ushort As[GB][AP];        // 64 x 264 x 2B = 33,792 B
    const int blk = blockIdx.x;
    const int tid = threadIdx.x;

    if (blk >= GEMM_BLKS) {
        // ---- direct bucket scatter (single pass) ----
        int f = (blk - GEMM_BLKS) * 256 + tid;
        if (f >= TOT_E) return;
        int k, e; decode_flat(f, k, e);
        int s, d;
        if (k == 0 && e >= EDGES) { s = d = e - EDGES; }
        else {
            const int* ei = (k == 0) ? ei0 : (k == 1) ? ei1 : ei2;
            s = ei[e]; d = ei[EDGES + e];
        }
        int pos = atomicAdd(&cnt[k * N_NODES + d], 1);
        if (pos < CAP)
            bucket[((size_t)k * N_NODES + d) * CAP + pos] = (ushort)s;
        return;
    }

    const int wave = tid >> 6, lane = tid & 63;
    const int row0 = blk * GB;
    const int wx   = wave * 128;         // this wave's output-col base
    const int lrow = lane & 15, lk = (lane >> 4) * 8;

    // ---- stage full-K A tile once: 64 rows x 256 cols bf16 ----
    #pragma unroll
    for (int j = 0; j < 8; j++) {
        int id = tid + 256 * j;          // 0..2047
        int r  = id >> 5;                // 32 uint4-slots per 512B row
        int c  = (id & 31) * 8;
        int gr = row0 + r;
        uint4 v = make_uint4(0u, 0u, 0u, 0u);
        if (gr < M)
            v = *(const uint4*)(Xb + (size_t)gr * IN_DIM + c);
        *(uint4*)&As[r][c] = v;
    }
    __syncthreads();                     // the ONLY barrier

    floatx4 acc[4][8];
    #pragma unroll
    for (int i = 0; i < 4; i++)
        #pragma unroll
        for (int j = 0; j < 8; j++)
            acc[i][j] = (floatx4){0.f, 0.f, 0.f, 0.f};

    #pragma unroll 2
    for (int k0 = 0; k0 < IN_DIM; k0 += 32) {
        short8 af[4], bf[8];
        #pragma unroll
        for (int ni = 0; ni < 8; ni++)
            bf[ni] = *(const short8*)(WT +
                (size_t)(wx + ni * 16 + lrow) * IN_DIM + k0 + lk);
        #pragma unroll
        for (int mi = 0; mi < 4; mi++)
            af[mi] = *(const short8*)&As[mi * 16 + lrow][k0 + lk];

        #pragma unroll
        for (int mi = 0; mi < 4; mi++)
            #pragma unroll
            for (int ni = 0; ni < 8; ni++)
                acc[mi][ni] = __builtin_amdgcn_mfma_f32_16x16x32_bf16(
                    bf[ni], af[mi], acc[mi][ni], 0, 0, 0);
    }

    const int csub = (lane >> 4) * 4;
    const bool left = (wx < HC);         // wave-uniform: waves 0,1 -> xlb; 2,3 -> xrb
    const float*  bvec = left ? b_l : b_r;
    ushort*       obuf = left ? xlb : xrb;
    const int     cbase = left ? wx : wx - HC;
    #pragma unroll
    for (int mi = 0; mi < 4; mi++) {
        int grow = row0 + mi * 16 + lrow;
        if (grow < M) {
            #pragma unroll
            for (int ni = 0; ni < 8; ni++) {
                int lc = cbase + ni * 16 + csub;
                floatx4 v = acc[mi][ni];
                const float4 b = *(const float4*)(bvec + lc);
                union { ushort s[4]; uint2 u; } o;
                o.s[0] = f2bf(v[0] + b.x);
                o.s[1] = f2bf(v[1] + b.y);
                o.s[2] = f2bf(v[2] + b.z);
                o.s[3] = f2bf(v[3] + b.w);
                *(uint2*)(obuf + (size_t)grow * HC + lc) = o.u;
            }
        }
    }
}

// ---------------------------------------------------------------------------
// node_all v10 (DPP head-reduce; ushort bucket row = 64B = one cache line):
// measured 125.6-126.5 µs at r14.
// ---------------------------------------------------------------------------
__global__ __launch_bounds__(192) void node_all(
    const ushort* __restrict__ xlb, const ushort* __restrict__ xrb,
    const int* __restrict__ cnt, const ushort* __restrict__ bucket,
    const float* __restrict__ att, const float* __restrict__ gw,
    const float* __restrict__ bias, float* __restrict__ out)
{
    __shared__ float lds[HOPS][CDIM];
    const int n    = blockIdx.x;
    const int k    = threadIdx.x >> 6;   // hop
    const int lane = threadIdx.x & 63;
    const int half = lane >> 5;          // which edge of the pair
    const int sub  = lane & 31;          // channel group: ch = sub*8 .. sub*8+7
    const unsigned laneoff = (unsigned)sub * 8;

    const int deg = min(cnt[k * N_NODES + n], CAP);
    const ushort* bk = bucket + ((size_t)k * N_NODES + n) * CAP;

    // xr channels for this lane (bf16 -> f32x2 pairs)
    uint4 rq = *(const uint4*)(xrb + (size_t)n * HC + laneoff);
    f32x2 rr[4] = { bf2x(rq.x), bf2x(rq.y), bf2x(rq.z), bf2x(rq.w) };

    // att pre-scaled by LOG2E: p is a log2-domain logit -> raw v_exp_f32
    const float4 a0 = ((const float4*)(att + (size_t)k * HC))[sub * 2 + 0];
    const float4 a1 = ((const float4*)(att + (size_t)k * HC))[sub * 2 + 1];
    f32x2 w2[4] = { {a0.x * LOG2E, a0.y * LOG2E}, {a0.z * LOG2E, a0.w * LOG2E},
                    {a1.x * LOG2E, a1.y * LOG2E}, {a1.z * LOG2E, a1.w * LOG2E} };

    float denom = 0.f;
    f32x2 acc2[4] = { {0.f,0.f}, {0.f,0.f}, {0.f,0.f}, {0.f,0.f} };

    if (deg > 0) {
        const int degm1 = deg - 1;
        int myS = (lane < deg) ? (int)bk[lane] : 0;
        const int npair = (deg + 1) >> 1;

        int s0 = __shfl(myS, min(half, degm1));
        uint4 q = *(const uint4*)(xlb + (unsigned)s0 * HC + laneoff);

        for (int j = 0; j < npair; j++) {
            int sn = __shfl(myS, min(2 * (j + 1) + half, degm1));
            uint4 qn = *(const uint4*)(xlb + (unsigned)sn * HC + laneoff);

            f32x2 f0 = bf2x(q.x), f1 = bf2x(q.y);
            f32x2 f2 = bf2x(q.z), f3 = bf2x(q.w);

            f32x2 pp = w2[0] * lrelu2(f0 + rr[0]);
            pp = __builtin_elementwise_fma(w2[1], lrelu2(f1 + rr[1]), pp);
            pp = __builtin_elementwise_fma(w2[2], lrelu2(f2 + rr[2]), pp);
            pp = __builtin_elementwise_fma(w2[3], lrelu2(f3 + rr[3]), pp);
            float p = pp.x + pp.y;

            // per-head reduce over 8 lanes: 3 DPP VALU adds
            p = dpp_xadd<DPP_XOR1>(p);
            p = dpp_xadd<DPP_XOR2>(p);
            p = dpp_xadd<DPP_HMIR>(p);

            bool valid = (2 * j + half) < deg;
            float ex = valid ? exp2_raw(p) : 0.f;
            denom += ex;
            f32x2 ex2 = { ex, ex };
            acc2[0] = __builtin_elementwise_fma(ex2, f0, acc2[0]);
            acc2[1] = __builtin_elementwise_fma(ex2, f1, acc2[1]);
            acc2[2] = __builtin_elementwise_fma(ex2, f2, acc2[2]);
            acc2[3] = __builtin_elementwise_fma(ex2, f3, acc2[3]);
            q = qn;
        }
    }

    // merge halves (xor-32): denom & acc are per-head after this.
    denom += __shfl_xor(denom, 32);
    const float inv = (denom > 0.f) ? 1.f / denom : 0.f;
    const float g   = gw[n * HOPS + k];
    const float* bb = bias + (size_t)k * CDIM + (size_t)(sub & 7) * 8;

    // per-head normalize FIRST, THEN head mean (xor-8, xor-16).
    #pragma unroll
    for (int i = 0; i < 4; i++) {
        acc2[i].x += __shfl_xor(acc2[i].x, 32);
        acc2[i].y += __shfl_xor(acc2[i].y, 32);
        acc2[i].x *= inv;
        acc2[i].y *= inv;
        acc2[i].x += __shfl_xor(acc2[i].x, 8);
        acc2[i].y += __shfl_xor(acc2[i].y, 8);
        acc2[i].x += __shfl_xor(acc2[i].x, 16);
        acc2[i].y += __shfl_xor(acc2[i].y, 16);
        if (lane < 8) {
            lds[k][lane * 8 + 2 * i]     = g * (acc2[i].x * 0.25f + bb[2 * i]);
            lds[k][lane * 8 + 2 * i + 1] = g * (acc2[i].y * 0.25f + bb[2 * i + 1]);
        }
    }
    __syncthreads();

    if (threadIdx.x < CDIM)
        out[(size_t)n * CDIM + threadIdx.x] =
            lds[0][threadIdx.x] + lds[1][threadIdx.x] + lds[2][threadIdx.x];
}

// ---------------------------------------------------------------------------
extern "C" void kernel_launch(void* const* d_in, const int* in_sizes, int n_in,
                              void* d_out, int out_size, void* d_ws, size_t ws_size,
                              hipStream_t stream)
{
    const float* x      = (const float*)d_in[0];
    const int*   ei0    = (const int*)d_in[1];
    const int*   ei1    = (const int*)d_in[2];
    const int*   ei2    = (const int*)d_in[3];
    const float* W_l    = (const float*)d_in[4];
    const float* b_l    = (const float*)d_in[5];
    const float* W_r    = (const float*)d_in[6];
    const float* b_r    = (const float*)d_in[7];
    const float* att    = (const float*)d_in[8];   // [3,4,64]
    const float* bias   = (const float*)d_in[9];   // [3,64]
    const float* W_gate = (const float*)d_in[10];  // [256,3]
    const float* b_gate = (const float*)d_in[11];  // [3]

    const size_t NHC = (size_t)N_NODES * HC;       // 12,800,000
    float* ws      = (float*)d_ws;
    float* gwbuf   = ws;                           // 150,000 floats
    int*   cnt     = (int*)(gwbuf + HOPS * N_NODES);         // 150,000 ints
    ushort* bucket = (ushort*)(cnt + HOPS * N_NODES);        // 3*N*CAP ushorts = 9.6 MB
    ushort* xlb    = bucket + (size_t)HOPS * N_NODES * CAP;  // NHC bf16
    ushort* xrb    = xlb + NHC;                    // NHC bf16
    ushort* Xb     = xrb + NHC;                    // NHC bf16
    ushort* WT     = Xb + NHC;                     // 131,072 bf16

    // gate + pack_x | pack_w | zero-cnt (memset folded in; no extra launch)
    prep_a<<<NB_GATE + NB_PACKW + NB_ZERO, 256, 0, stream>>>(
        x, W_gate, b_gate, gwbuf, Xb, W_l, W_r, WT, cnt);

    // gemm v4 + single-pass scatter (ushort bucket: 9.6 MB footprint)
    gemm_scatter<<<FUSED_BLKS, 256, 0, stream>>>(
        Xb, WT, b_l, b_r, xlb, xrb, N_NODES,
        ei0, ei1, ei2, cnt, bucket);

    // fused logits + softmax + aggregate + head-mean + gate combine
    node_all<<<N_NODES, 192, 0, stream>>>(
        xlb, xrb, cnt, bucket, att, gwbuf, bias, (float*)d_out);
}